// Round 1
// baseline (7214.780 us; speedup 1.0000x reference)
//
#include <hip/hip_runtime.h>
#include <hip/hip_bf16.h>

// CGCNN-PyG forward. Sizes fixed per reference.
#define N_ATOMS 50000
#define N_EDGES 1200000
#define FA 92
#define FB 41
#define DD 64
#define HH 128
#define LL 3
#define GG 1024
#define PADW 65          // 64 + 1 pad -> conflict-free row/col LDS access
#define NBATCH (N_EDGES / 64)   // 18750, exact

// stable softplus matching jax.nn.softplus = max(x,0) + log1p(exp(-|x|))
__device__ __forceinline__ float sp_f(float x) {
  float ax = fabsf(x);
  float e  = __expf(-ax);
  float l  = __logf(1.f + e);   // e in (0,1] -> 1+e in (1,2], full precision
  return fmaxf(x, 0.f) + l;
}

// 64x64 matvec, lane=edge mode: u[] in regs (per-edge vector), WT d-major
// (WT[d][k], k contiguous -> uniform s_load stream), result written to LDS
// transpose buffer T[d][lane].
template<bool HASBIAS>
__device__ __forceinline__ void matvec64(const float (&u)[DD], const float* __restrict__ WT,
                                         const float* __restrict__ bias,
                                         float* __restrict__ T, int lane) {
  for (int dt = 0; dt < DD; dt += 8) {     // runtime loop keeps I$ small
    float acc[8];
#pragma unroll
    for (int t = 0; t < 8; ++t) acc[t] = HASBIAS ? bias[dt + t] : 0.f;
#pragma unroll
    for (int k = 0; k < DD; ++k) {
#pragma unroll
      for (int t = 0; t < 8; ++t) acc[t] = fmaf(u[k], WT[(dt + t) * DD + k], acc[t]);
    }
#pragma unroll
    for (int t = 0; t < 8; ++t) T[(dt + t) * PADW + lane] = acc[t];
  }
}

// h = x @ atom_W + atom_b   [N,92]->[N,64]
__global__ __launch_bounds__(256)
void atom_embed_kernel(const float* __restrict__ x, const float* __restrict__ W,
                       const float* __restrict__ b, float* __restrict__ h) {
  int n = blockIdx.x * 4 + (threadIdx.x >> 6);
  int lane = threadIdx.x & 63;
  if (n >= N_ATOMS) return;
  float acc = b[lane];
  const float* xr = x + (size_t)n * FA;
#pragma unroll
  for (int k = 0; k < FA; ++k) acc = fmaf(xr[k], W[k * DD + lane], acc);
  h[(size_t)n * DD + lane] = acc;
}

// e = edge_attr @ bond_W + bond_b   [E,41]->[E,64]
__global__ __launch_bounds__(256)
void bond_embed_kernel(const float* __restrict__ ea, const float* __restrict__ W,
                       const float* __restrict__ b, float* __restrict__ e) {
  int eg = blockIdx.x * 4 + (threadIdx.x >> 6);
  int lane = threadIdx.x & 63;
  if (eg >= N_EDGES) return;
  float acc = b[lane];
  const float* er = ea + (size_t)eg * FB;
#pragma unroll
  for (int k = 0; k < FB; ++k) acc = fmaf(er[k], W[k * DD + lane], acc);
  e[(size_t)eg * DD + lane] = acc;
}

// Ha = h@Wa, Hb = h@Wb, Hc = h@Wc  (node-side precompute of concat-matmul parts)
__global__ __launch_bounds__(256)
void node_pre_kernel(const float* __restrict__ h, const float* __restrict__ Wa,
                     const float* __restrict__ Wb, const float* __restrict__ Wc,
                     float* __restrict__ Ha, float* __restrict__ Hb, float* __restrict__ Hc) {
  int n = blockIdx.x * 4 + (threadIdx.x >> 6);
  int lane = threadIdx.x & 63;
  if (n >= N_ATOMS) return;
  float a = 0.f, bb = 0.f, c = 0.f;
  const float* hr = h + (size_t)n * DD;
#pragma unroll
  for (int k = 0; k < DD; ++k) {
    float hv = hr[k];
    a  = fmaf(hv, Wa[k * DD + lane], a);
    bb = fmaf(hv, Wb[k * DD + lane], bb);
    c  = fmaf(hv, Wc[k * DD + lane], c);
  }
  Ha[(size_t)n * DD + lane] = a;
  Hb[(size_t)n * DD + lane] = bb;
  Hc[(size_t)n * DD + lane] = c;
}

// transpose the 4 per-edge 64x64 matrices of every layer to d-major [d][k]
__global__ void prep_wt_kernel(const float* __restrict__ eu_W1, const float* __restrict__ eu_W2,
                               const float* __restrict__ nu_W1, const float* __restrict__ nu_W2,
                               float* __restrict__ wt) {
  int tid = blockIdx.x * 256 + threadIdx.x;
  if (tid >= LL * 4 * DD * DD) return;
  int mat = tid >> 12;          // /4096
  int idx = tid & 4095;
  int layer = mat >> 2, m = mat & 3;
  int d = idx >> 6, k = idx & 63;
  float v;
  if      (m == 0) v = eu_W1[layer * 192 * DD + (128 + k) * DD + d];  // W1c (e part of eu_W1)
  else if (m == 1) v = eu_W2[layer * DD * DD + k * DD + d];           // W2
  else if (m == 2) v = nu_W1[layer * 128 * DD + (64 + k) * DD + d];   // W1b (e part of nu_W1)
  else             v = nu_W2[layer * DD * DD + k * DD + d];           // nW2
  wt[layer * 4 * DD * DD + m * DD * DD + d * DD + k] = v;
}

// Fused per-edge layer: e_new = W2^T sp(Ha[r]+Hb[c]+W1c^T e + b1) + b2  (written in place)
//                       msg   = nW2^T sp(Hc[r]+W1b^T e_new + nb1) + nb2 -> atomicAdd h_new[c]
// lane=edge compute (weights via scalar loads), lane=channel I/O via per-wave LDS transpose.
__global__ __launch_bounds__(256, 2)
void edge_layer_kernel(const float* __restrict__ Ha, const float* __restrict__ Hb,
                       const float* __restrict__ Hc, float* __restrict__ e_g,
                       const int* __restrict__ row_g, const int* __restrict__ col_g,
                       const float* __restrict__ W1cT, const float* __restrict__ W2T,
                       const float* __restrict__ W1bT, const float* __restrict__ nW2T,
                       const float* __restrict__ b1, const float* __restrict__ b2,
                       const float* __restrict__ nb1, const float* __restrict__ nb2,
                       float* __restrict__ hnew, int nbatch) {
  __shared__ float lds[4][DD * PADW];   // 66,560 B -> 2 blocks/CU
  const int wid = threadIdx.x >> 6;
  const int lane = threadIdx.x & 63;
  float* T = lds[wid];
  const float b1l = b1[lane];
  const float nb1l = nb1[lane];
  const int w0 = blockIdx.x * 4 + wid;
  const int nw = gridDim.x * 4;

  for (int b = w0; b < nbatch; b += nw) {
    const int ebase = b * 64;
    // stage this wave's 64 edges' e-vectors (coalesced), lane = channel
#pragma unroll 8
    for (int el = 0; el < 64; ++el)
      T[lane * PADW + el] = e_g[(size_t)(ebase + el) * DD + lane];

    float u[DD];
#pragma unroll
    for (int k = 0; k < DD; ++k) u[k] = T[k * PADW + lane];   // lane = edge
    matvec64<false>(u, W1cT, nullptr, T, lane);               // partial t1 -> T

    // += Ha[row] + Hb[col] + b1, softplus (fused gather, lane = channel)
#pragma unroll 8
    for (int el = 0; el < 64; ++el) {
      int r = row_g[ebase + el], c = col_g[ebase + el];
      float v = T[lane * PADW + el] + Ha[(size_t)r * DD + lane] + Hb[(size_t)c * DD + lane] + b1l;
      T[lane * PADW + el] = sp_f(v);
    }

#pragma unroll
    for (int k = 0; k < DD; ++k) u[k] = T[k * PADW + lane];
    matvec64<true>(u, W2T, b2, T, lane);                      // e_new -> T

    // write updated e (in place; edges are disjoint rows)
#pragma unroll 8
    for (int el = 0; el < 64; ++el)
      e_g[(size_t)(ebase + el) * DD + lane] = T[lane * PADW + el];

#pragma unroll
    for (int k = 0; k < DD; ++k) u[k] = T[k * PADW + lane];
    matvec64<false>(u, W1bT, nullptr, T, lane);               // partial m1 -> T

    // += Hc[row] + nb1, softplus
#pragma unroll 8
    for (int el = 0; el < 64; ++el) {
      int r = row_g[ebase + el];
      float v = T[lane * PADW + el] + Hc[(size_t)r * DD + lane] + nb1l;
      T[lane * PADW + el] = sp_f(v);
    }

#pragma unroll
    for (int k = 0; k < DD; ++k) u[k] = T[k * PADW + lane];
    matvec64<true>(u, nW2T, nb2, T, lane);                    // msg -> T

    // scatter-add messages to destination nodes
#pragma unroll 8
    for (int el = 0; el < 64; ++el) {
      int c = col_g[ebase + el];
      atomicAdd(&hnew[(size_t)c * DD + lane], T[lane * PADW + el]);
    }
  }
}

// per-channel sum & sumsq over h_new
__global__ __launch_bounds__(256)
void bn_stats_kernel(const float* __restrict__ hnew, float* __restrict__ stats) {
  int lane = threadIdx.x & 63, wid = threadIdx.x >> 6;
  int start = blockIdx.x * 4 + wid, step = gridDim.x * 4;
  float s = 0.f, q = 0.f;
  for (int n = start; n < N_ATOMS; n += step) {
    float v = hnew[(size_t)n * DD + lane];
    s += v;
    q = fmaf(v, v, q);
  }
  atomicAdd(&stats[lane], s);
  atomicAdd(&stats[DD + lane], q);
}

// h = sp(BN(h_new)) + h
__global__ __launch_bounds__(256)
void bn_apply_kernel(const float* __restrict__ hnew, const float* __restrict__ stats,
                     const float* __restrict__ gamma, const float* __restrict__ beta,
                     float* __restrict__ h) {
  int idx = blockIdx.x * 256 + threadIdx.x;   // N*64 = 3.2M exact
  int d = idx & 63;
  const float invN = 1.f / (float)N_ATOMS;
  float mu = stats[d] * invN;
  float var = fmaxf(stats[DD + d] * invN - mu * mu, 0.f);
  float inv = 1.f / sqrtf(var + 1e-5f);
  float hb = (hnew[idx] - mu) * inv * gamma[d] + beta[d];
  h[idx] = sp_f(hb) + h[idx];
}

__global__ __launch_bounds__(256)
void pool_kernel(const float* __restrict__ h, const int* __restrict__ batch,
                 float* __restrict__ gsum, float* __restrict__ cnt) {
  int n = blockIdx.x * 4 + (threadIdx.x >> 6);
  int lane = threadIdx.x & 63;
  if (n >= N_ATOMS) return;
  int b = batch[n];
  atomicAdd(&gsum[(size_t)b * DD + lane], h[(size_t)n * DD + lane]);
  if (lane == 0) atomicAdd(&cnt[b], 1.f);
}

__global__ __launch_bounds__(128)
void pred_kernel(const float* __restrict__ gsum, const float* __restrict__ cnt,
                 const float* __restrict__ W1, const float* __restrict__ b1,
                 const float* __restrict__ W2, const float* __restrict__ b2,
                 const float* __restrict__ W3, const float* __restrict__ b3,
                 float* __restrict__ out) {
  __shared__ float sg[DD];
  __shared__ float so[HH];
  int g = blockIdx.x, t = threadIdx.x;
  if (t < DD) sg[t] = gsum[(size_t)g * DD + t] / fmaxf(cnt[g], 1.f);
  __syncthreads();
  float a = b1[t];
#pragma unroll
  for (int k = 0; k < DD; ++k) a = fmaf(sg[k], W1[k * HH + t], a);
  a = sp_f(a);
  so[t] = a;
  __syncthreads();
  float o = b2[t];
#pragma unroll
  for (int k = 0; k < HH; ++k) o = fmaf(so[k], W2[k * HH + t], o);
  o = sp_f(o);
  float contrib = o * W3[t];
  __syncthreads();
  so[t] = contrib;
  __syncthreads();
  if (t < 64) so[t] += so[t + 64];
  __syncthreads();
  if (t == 0) {
    float s = 0.f;
    for (int k = 0; k < 64; ++k) s += so[k];
    out[g] = s + b3[0];
  }
}

extern "C" void kernel_launch(void* const* d_in, const int* in_sizes, int n_in,
                              void* d_out, int out_size, void* d_ws, size_t ws_size,
                              hipStream_t stream) {
  const float* x         = (const float*)d_in[0];
  const float* edge_attr = (const float*)d_in[1];
  const int*   eidx      = (const int*)d_in[2];
  const int*   batch     = (const int*)d_in[3];
  const float* atom_W    = (const float*)d_in[4];
  const float* atom_b    = (const float*)d_in[5];
  const float* bond_W    = (const float*)d_in[6];
  const float* bond_b    = (const float*)d_in[7];
  const float* nu_W1     = (const float*)d_in[8];
  const float* nu_b1     = (const float*)d_in[9];
  const float* nu_W2     = (const float*)d_in[10];
  const float* nu_b2     = (const float*)d_in[11];
  const float* eu_W1     = (const float*)d_in[12];
  const float* eu_b1     = (const float*)d_in[13];
  const float* eu_W2     = (const float*)d_in[14];
  const float* eu_b2     = (const float*)d_in[15];
  const float* bn_gamma  = (const float*)d_in[16];
  const float* bn_beta   = (const float*)d_in[17];
  const float* pW1       = (const float*)d_in[18];
  const float* pb1       = (const float*)d_in[19];
  const float* pW2       = (const float*)d_in[20];
  const float* pb2       = (const float*)d_in[21];
  const float* pW3       = (const float*)d_in[22];
  const float* pb3       = (const float*)d_in[23];
  float* out = (float*)d_out;

  // workspace layout (floats). Total ~92.9M floats = 372 MB.
  float* ws   = (float*)d_ws;
  float* h    = ws;                  // 3.2M
  float* hnew = ws + 3200000;        // 3.2M
  float* Ha   = ws + 6400000;        // 3.2M
  float* Hb   = ws + 9600000;        // 3.2M
  float* Hc   = ws + 12800000;       // 3.2M
  float* stats= ws + 16000000;       // 128
  float* gsum = ws + 16000128;       // 65536
  float* cnt  = ws + 16065664;       // 1024
  float* wt   = ws + 16066688;       // 49152 (3 layers x 4 mats x 64x64, d-major)
  float* e    = ws + 16115840;       // 76.8M

  const int* row = eidx;
  const int* col = eidx + N_EDGES;

  prep_wt_kernel<<<192, 256, 0, stream>>>(eu_W1, eu_W2, nu_W1, nu_W2, wt);
  atom_embed_kernel<<<N_ATOMS / 4, 256, 0, stream>>>(x, atom_W, atom_b, h);
  bond_embed_kernel<<<N_EDGES / 4, 256, 0, stream>>>(edge_attr, bond_W, bond_b, e);

  for (int i = 0; i < LL; ++i) {
    const float* Wa = eu_W1 + (size_t)i * 192 * DD;            // h[row] part of eu_W1
    const float* Wb = Wa + 64 * DD;                            // h[col] part
    const float* Wc = nu_W1 + (size_t)i * 128 * DD;            // h[row] part of nu_W1
    node_pre_kernel<<<N_ATOMS / 4, 256, 0, stream>>>(h, Wa, Wb, Wc, Ha, Hb, Hc);
    hipMemsetAsync(hnew, 0, (size_t)N_ATOMS * DD * sizeof(float), stream);
    hipMemsetAsync(stats, 0, 128 * sizeof(float), stream);
    const float* wl = wt + (size_t)i * 4 * DD * DD;
    edge_layer_kernel<<<512, 256, 0, stream>>>(
        Ha, Hb, Hc, e, row, col,
        wl, wl + DD * DD, wl + 2 * DD * DD, wl + 3 * DD * DD,
        eu_b1 + i * DD, eu_b2 + i * DD, nu_b1 + i * DD, nu_b2 + i * DD,
        hnew, NBATCH);
    bn_stats_kernel<<<128, 256, 0, stream>>>(hnew, stats);
    bn_apply_kernel<<<N_ATOMS * DD / 256, 256, 0, stream>>>(
        hnew, stats, bn_gamma + i * DD, bn_beta + i * DD, h);
  }

  hipMemsetAsync(gsum, 0, (65536 + 1024) * sizeof(float), stream);
  pool_kernel<<<N_ATOMS / 4, 256, 0, stream>>>(h, batch, gsum, cnt);
  pred_kernel<<<GG, 128, 0, stream>>>(gsum, cnt, pW1, pb1, pW2, pb2, pW3, pb3, out);
}